// Round 10
// baseline (138.240 us; speedup 1.0000x reference)
//
#include <hip/hip_runtime.h>

typedef __attribute__((ext_vector_type(8))) short bf16x8;
typedef __attribute__((ext_vector_type(4))) float f32x4;
typedef __attribute__((ext_vector_type(4))) unsigned short u16x4;

#define DEVFN static __device__ __forceinline__

// hardware packed f32->bf16 (RNE): lo -> low16, hi -> high16
DEVFN unsigned cvtpk(float lo, float hi) {
  unsigned r;
  asm("v_cvt_pk_bf16_f32 %0, %1, %2" : "=v"(r) : "v"(lo), "v"(hi));
  return r;
}
DEVFN unsigned short cvt1(float x) {
  unsigned r;
  asm("v_cvt_pk_bf16_f32 %0, %1, %1" : "=v"(r) : "v"(x));
  return (unsigned short)r;
}
DEVFN float fexp2(float x) {  // raw v_exp_f32 (2^x), no libm fixups
  float r;
  asm("v_exp_f32 %0, %1" : "=v"(r) : "v"(x));
  return r;
}
DEVFN float bf2f(unsigned short s) { return __uint_as_float(((unsigned)s) << 16); }

// async 16B global->LDS. LDS dest must be wave-uniform base (HW adds lane*16).
DEVFN void gld16(const void* g, void* l) {
  __builtin_amdgcn_global_load_lds(
      (const __attribute__((address_space(1))) unsigned int*)g,
      (__attribute__((address_space(3))) unsigned int*)l, 16, 0, 0);
}

// convert up to 4 f32 matrices (perMat elems each) to bf16, concatenated dst
__global__ __launch_bounds__(256, 8) void prep_cast(
    const float* __restrict__ s0, const float* __restrict__ s1,
    const float* __restrict__ s2, const float* __restrict__ s3,
    unsigned short* __restrict__ dst, int perMat) {
  const float* s = blockIdx.y == 0 ? s0 : blockIdx.y == 1 ? s1
                   : blockIdx.y == 2 ? s2 : s3;
  size_t base = (size_t)blockIdx.y * perMat;
  size_t idx = ((size_t)blockIdx.x * 256 + threadIdx.x) * 8;
  float4 a = *(const float4*)(s + idx);
  float4 b = *(const float4*)(s + idx + 4);
  uint4 o;
  o.x = cvtpk(a.x, a.y); o.y = cvtpk(a.z, a.w);
  o.z = cvtpk(b.x, b.y); o.w = cvtpk(b.z, b.w);
  *(uint4*)(dst + base + idx) = o;
}

// C = A (8192xK=512) * W^T (W N=512xK=512 row-major). Tile 128x64, BK=64,
// double-buffered LDS. LDS rows 128B; 16B chunk c of row r at (c^(r&7)) ->
// conflict-free ds_read_b128. mode 0=Q 1=K 2=V 3=P, 4=OUT.
// SWZ: 1D grid 2048, XCD-bijective decode keeping one A-panel's n-tiles on
// one XCD. !SWZ: grid (m,n,mode).
template <bool AF32, bool SWZ>
__global__ __launch_bounds__(256, 3) void gemm_bt(
    const void* A0, const void* A1, const void* A2, const void* A3,
    const unsigned short* __restrict__ Wb, const float* b0, const float* b1,
    const float* b2, int mode_base,
    unsigned short* __restrict__ qout, float* __restrict__ cache,
    unsigned short* __restrict__ vtout, unsigned short* __restrict__ pout,
    float* __restrict__ fout) {
  __shared__ alignas(16) char Als[2][128 * 128];
  __shared__ alignas(16) char Bls[2][64 * 128];
  const int tid = threadIdx.x;
  const int lane = tid & 63, w = tid >> 6;
  const int wr = (w >> 1) * 64, wc = (w & 1) * 32;
  const int lg = lane >> 4, lr = lane & 15;
  int m0, n0, mz;
  if constexpr (SWZ) {
    int id = blockIdx.x;
    int xcd = id & 7, j = id >> 3;
    n0 = (j & 7) * 64;
    mz = (j >> 3) & 3;
    m0 = (xcd * 8 + (j >> 5)) * 128;
  } else {
    m0 = blockIdx.x * 128;
    n0 = blockIdx.y * 64;
    mz = blockIdx.z;
  }
  const int mode = mode_base + mz;
  const void* Ap = (mode == 1) ? A1 : (mode == 2) ? A2 : (mode == 3) ? A3 : A0;
  const unsigned short* Wp = Wb + (size_t)mz * 262144;
  const float* bias = (mode == 0 || mode == 4) ? b0
                      : (mode == 1) ? b1 : (mode == 2) ? b2 : nullptr;

  float4 ra[8];
  auto loadA = [&](int k0) {
    const float* Af = (const float*)Ap;
#pragma unroll
    for (int rep = 0; rep < 4; rep++) {
      int cid = rep * 256 + tid;
      int row = cid >> 3, c = cid & 7;
      const float* src = Af + (size_t)(m0 + row) * 512 + k0 + c * 8;
      ra[rep * 2] = *(const float4*)(src);
      ra[rep * 2 + 1] = *(const float4*)(src + 4);
    }
  };
  auto writeA = [&](int buf) {
#pragma unroll
    for (int rep = 0; rep < 4; rep++) {
      int cid = rep * 256 + tid;
      int row = cid >> 3, c = cid & 7;
      uint4 o;
      o.x = cvtpk(ra[rep * 2].x, ra[rep * 2].y);
      o.y = cvtpk(ra[rep * 2].z, ra[rep * 2].w);
      o.z = cvtpk(ra[rep * 2 + 1].x, ra[rep * 2 + 1].y);
      o.w = cvtpk(ra[rep * 2 + 1].z, ra[rep * 2 + 1].w);
      *(uint4*)(Als[buf] + row * 128 + ((c ^ (row & 7)) << 4)) = o;
    }
  };
  auto stageA_lds = [&](int buf, int k0) {  // bf16 A: direct async to LDS
    const unsigned short* Ab = (const unsigned short*)Ap;
#pragma unroll
    for (int rep = 0; rep < 4; rep++) {
      int cid = rep * 256 + tid;
      int row = cid >> 3, c = cid & 7;
      gld16(Ab + (size_t)(m0 + row) * 512 + k0 + ((c ^ (row & 7)) << 3),
            Als[buf] + ((rep * 256 + (w << 6)) << 4));
    }
  };
  auto stageB = [&](int buf, int k0) {
#pragma unroll
    for (int rep = 0; rep < 2; rep++) {
      int cid = rep * 256 + tid;
      int row = cid >> 3, c = cid & 7;
      gld16(Wp + (size_t)(n0 + row) * 512 + k0 + ((c ^ (row & 7)) << 3),
            Bls[buf] + ((rep * 256 + (w << 6)) << 4));
    }
  };

  f32x4 acc[4][2];
#pragma unroll
  for (int i = 0; i < 4; i++)
#pragma unroll
    for (int j = 0; j < 2; j++) acc[i][j] = (f32x4)(0.f);

  if constexpr (AF32) { loadA(0); writeA(0); } else { stageA_lds(0, 0); }
  stageB(0, 0);
  __syncthreads();
  int cur = 0;
  for (int k0 = 0; k0 < 512; k0 += 64) {
    bool more = (k0 + 64 < 512);
    if (more) {
      if constexpr (AF32) loadA(k0 + 64); else stageA_lds(cur ^ 1, k0 + 64);
      stageB(cur ^ 1, k0 + 64);
    }
#pragma unroll
    for (int ks = 0; ks < 2; ks++) {
      bf16x8 af[4], bfr[2];
#pragma unroll
      for (int i = 0; i < 4; i++) {
        int row = wr + i * 16 + lr;
        af[i] = *(const bf16x8*)(Als[cur] + row * 128 + (((ks * 4 + lg) ^ (row & 7)) << 4));
      }
#pragma unroll
      for (int j = 0; j < 2; j++) {
        int row = wc + j * 16 + lr;
        bfr[j] = *(const bf16x8*)(Bls[cur] + row * 128 + (((ks * 4 + lg) ^ (row & 7)) << 4));
      }
#pragma unroll
      for (int i = 0; i < 4; i++)
#pragma unroll
        for (int j = 0; j < 2; j++)
          acc[i][j] = __builtin_amdgcn_mfma_f32_16x16x32_bf16(af[i], bfr[j],
                                                              acc[i][j], 0, 0, 0);
    }
    if (more) { if constexpr (AF32) writeA(cur ^ 1); }
    __syncthreads();
    cur ^= 1;
  }

#pragma unroll
  for (int i = 0; i < 4; i++) {
#pragma unroll
    for (int j = 0; j < 2; j++) {
      int colg = n0 + wc + j * 16 + lr;
      float bc = bias ? bias[colg] : 0.f;
      if (mode == 4) {
#pragma unroll
        for (int r = 0; r < 4; r++) {
          int rowg = m0 + wr + i * 16 + lg * 4 + r;
          fout[(size_t)rowg * 512 + colg] = acc[i][j][r] + bc;
        }
      } else {
        int rbase = m0 + wr + i * 16 + lg * 4;
        int b = rbase >> 10, t = rbase & 1023, h = colg >> 6, dk = colg & 63;
        size_t bht = (size_t)(b * 8 + h) * 1024 + t;
        if (mode == 0) {
#pragma unroll
          for (int r = 0; r < 4; r++) qout[(bht + r) * 64 + dk] = cvt1(acc[i][j][r] + bc);
        } else if (mode == 1) {
#pragma unroll
          for (int r = 0; r < 4; r++) cache[(bht + r) * 128 + dk] = acc[i][j][r] + bc;
        } else if (mode == 3) {
#pragma unroll
          for (int r = 0; r < 4; r++) pout[(bht + r) * 64 + dk] = cvt1(acc[i][j][r]);
        } else {
          float vv[4];
#pragma unroll
          for (int r = 0; r < 4; r++) {
            vv[r] = acc[i][j][r] + bc;
            cache[(bht + r) * 128 + 64 + dk] = vv[r];
          }
          uint2 pv;
          pv.x = cvtpk(vv[0], vv[1]);
          pv.y = cvtpk(vv[2], vv[3]);
          *(uint2*)(vtout + ((size_t)(b * 8 + h) * 64 + dk) * 1024 + t) = pv;
        }
      }
    }
  }
}

// in-place: p (bf16, in kp buffer) + k (f32 cache) -> kp bf16; c = u.k + v.p
__global__ __launch_bounds__(256, 4) void fuse_kp(
    const float* __restrict__ kcache, unsigned short* __restrict__ kp,
    const float* __restrict__ ub, const float* __restrict__ vb,
    float* __restrict__ cb) {
  int tid = threadIdx.x;
  int row = blockIdx.x * 16 + (tid >> 4);
  int g = tid & 15;
  int h = (row >> 10) & 7;
  float4 k4 = *(const float4*)(kcache + (size_t)row * 128 + g * 4);
  u16x4 p4 = *(const u16x4*)(kp + (size_t)row * 64 + g * 4);
  float4 uu = *(const float4*)(ub + h * 64 + g * 4);
  float4 vv = *(const float4*)(vb + h * 64 + g * 4);
  float kf[4] = {k4.x, k4.y, k4.z, k4.w};
  float uf[4] = {uu.x, uu.y, uu.z, uu.w};
  float vf[4] = {vv.x, vv.y, vv.z, vv.w};
  float part = 0.f;
  float s[4];
#pragma unroll
  for (int j = 0; j < 4; j++) {
    float pf = bf2f((unsigned short)p4[j]);
    s[j] = kf[j] + pf;
    part += uf[j] * kf[j] + vf[j] * pf;
  }
  uint2 o;
  o.x = cvtpk(s[0], s[1]);
  o.y = cvtpk(s[2], s[3]);
  *(uint2*)(kp + (size_t)row * 64 + g * 4) = o;
#pragma unroll
  for (int sft = 1; sft < 16; sft <<= 1) part += __shfl_xor(part, sft, 64);
  if (g == 0) cb[row] = part;
}

__global__ __launch_bounds__(256, 8) void pack_mask(
    const int* __restrict__ m, unsigned long long* __restrict__ mb) {
  int word = blockIdx.x * 4 + (threadIdx.x >> 6);
  int lane = threadIdx.x & 63;
  int v = m[(size_t)(word >> 4) * 1024 + (word & 15) * 64 + lane];
  unsigned long long bal = __ballot(v != 0);
  if (lane == 0) mb[word] = bal;
}

// flash attn: scores = (q.kp + c)*0.125, exp2-domain softmax vs fixed ref M=24.
// 8 waves x 16 q-rows = 128 q-rows per block; KVBLK=64, 16 tiles.
// T4 counted-vmcnt pipeline: 3 KP/VT buffers, prefetch distance 2, raw
// s_barrier with vmcnt(2) (freshest stage stays in flight across barriers).
// cb preloaded to LDS so the loop's only VMEM is the stage.
// 1D grid 512, XCD-swizzled: XCD x hosts bh in [8x,8x+8) -> per-XCD KV in L2.
__global__ __launch_bounds__(512, 2) void attn_kernel(
    const unsigned short* __restrict__ qw, const unsigned short* __restrict__ kpw,
    const unsigned short* __restrict__ vtw, const float* __restrict__ cb,
    const unsigned long long* __restrict__ mbits, unsigned short* __restrict__ ow) {
  __shared__ alignas(16) char KPls[3][64 * 128];  // 24 KB
  __shared__ alignas(16) char VTls[3][64 * 128];  // 24 KB
  __shared__ alignas(16) char Pls[8][16 * 128];   // 16 KB
  __shared__ float cvLS[1024];                    // 4 KB

  const int tid = threadIdx.x;
  const int lane = tid & 63, w = tid >> 6;
  const int lg = lane >> 4, lr = lane & 15;
  const int l = blockIdx.x;
  const int bh = (l & 7) * 8 + ((l >> 3) >> 3);
  const int t0 = ((l >> 3) & 7) * 128;
  const int b = bh >> 3;
  const int h = bh & 7;
  const float NEG = -3.0e38f;
  const float SC = 0.125f * 1.44269504088896f;  // log2e folded in
  const float MREF = 24.0f;                     // fixed softmax reference

  // preload cv (scaled) into LDS
  cvLS[tid] = cb[(size_t)bh * 1024 + tid] * SC;
  cvLS[512 + tid] = cb[(size_t)bh * 1024 + 512 + tid] * SC;

  const size_t qrow0 = (size_t)bh * 1024 + t0 + w * 16;
  bf16x8 qf[2];
#pragma unroll
  for (int ks = 0; ks < 2; ks++)
    qf[ks] = *(const bf16x8*)(qw + (qrow0 + lr) * 64 + ks * 32 + lg * 8);

  // precompute wave-wide mask-full flag (16 rows x 16 words per wave)
  bool wave_full;
  {
    unsigned long long accm = ~0ull;
#pragma unroll
    for (int r = 0; r < 4; r++) {
      int row = t0 + w * 16 + lg * 4 + r;
      accm &= mbits[((size_t)b * 1024 + row) * 16 + lr];
    }
    wave_full = __all(accm == ~0ull);
  }

  f32x4 oacc[4];
#pragma unroll
  for (int d = 0; d < 4; d++) oacc[d] = (f32x4)(0.f);
  float mrow[4], lsum[4];
#pragma unroll
  for (int r = 0; r < 4; r++) { mrow[r] = MREF; lsum[r] = 0.f; }

  // stage one 64-row kv tile: 2 gld16/thread (KP 8KB + VT 8KB)
  auto stage = [&](int buf, int s0) {
    const size_t kr0 = (size_t)bh * 1024 + s0;
    int row = tid >> 3, c = tid & 7;
    gld16(kpw + (kr0 + row) * 64 + ((c ^ (row & 7)) << 3),
          KPls[buf] + ((w << 6) << 4));
    gld16(vtw + ((size_t)bh * 64 + row) * 1024 + s0 + ((c ^ (row & 7)) << 3),
          VTls[buf] + ((w << 6) << 4));
  };

  stage(0, 0);
  stage(1, 64);
  __syncthreads();  // prologue: full drain (stage0+1 landed, cvLS visible)

  for (int t = 0; t < 16; ++t) {
    const int cur = t % 3;
    if (t + 2 < 16) stage((t + 2) % 3, (t + 2) * 64);

    const int s0 = t * 64;
    float cv2[4];
#pragma unroll
    for (int st = 0; st < 4; st++) cv2[st] = cvLS[s0 + st * 16 + lr];

    f32x4 sacc[4];
    __builtin_amdgcn_s_setprio(1);
#pragma unroll
    for (int st = 0; st < 4; st++) {
      sacc[st] = (f32x4)(0.f);
#pragma unroll
      for (int ks = 0; ks < 2; ks++) {
        int row = st * 16 + lr;
        bf16x8 kf = *(const bf16x8*)(KPls[cur] + row * 128 +
                                     (((ks * 4 + lg) ^ (row & 7)) << 4));
        sacc[st] = __builtin_amdgcn_mfma_f32_16x16x32_bf16(qf[ks], kf, sacc[st], 0, 0, 0);
      }
    }
    __builtin_amdgcn_s_setprio(0);

    unsigned pbp[4][2];
    if (wave_full) {
#pragma unroll
      for (int st = 0; st < 4; st++) {
        float p0 = fexp2(fmaf(sacc[st][0], SC, cv2[st]) - mrow[0]);
        float p1 = fexp2(fmaf(sacc[st][1], SC, cv2[st]) - mrow[1]);
        float p2 = fexp2(fmaf(sacc[st][2], SC, cv2[st]) - mrow[2]);
        float p3 = fexp2(fmaf(sacc[st][3], SC, cv2[st]) - mrow[3]);
        lsum[0] += p0; lsum[1] += p1; lsum[2] += p2; lsum[3] += p3;
        pbp[st][0] = cvtpk(p0, p1);
        pbp[st][1] = cvtpk(p2, p3);
      }
    } else {
      // recompute-based slow path (general masks)
      unsigned long long mb1[4];
#pragma unroll
      for (int r = 0; r < 4; r++)
        mb1[r] = mbits[((size_t)b * 1024 + (t0 + w * 16 + lg * 4 + r)) * 16 + (s0 >> 6)];
      float mx[4] = {NEG, NEG, NEG, NEG};
#pragma unroll
      for (int st = 0; st < 4; st++) {
        int bit = st * 16 + lr;
#pragma unroll
        for (int r = 0; r < 4; r++) {
          if ((mb1[r] >> bit) & 1ull)
            mx[r] = fmaxf(mx[r], fmaf(sacc[st][r], SC, cv2[st]));
        }
      }
      float scale[4];
#pragma unroll
      for (int r = 0; r < 4; r++) {
#pragma unroll
        for (int o = 1; o < 16; o <<= 1) mx[r] = fmaxf(mx[r], __shfl_xor(mx[r], o, 64));
        float mn = fmaxf(mrow[r], mx[r]);
        scale[r] = (mn == mrow[r]) ? 1.f : fexp2(mrow[r] - mn);
        mrow[r] = mn;
        lsum[r] *= scale[r];
      }
#pragma unroll
      for (int st = 0; st < 4; st++) {
        int bit = st * 16 + lr;
        float pr[4];
#pragma unroll
        for (int r = 0; r < 4; r++) {
          bool on = (mb1[r] >> bit) & 1ull;
          pr[r] = on ? fexp2(fmaf(sacc[st][r], SC, cv2[st]) - mrow[r]) : 0.f;
          lsum[r] += pr[r];
        }
        pbp[st][0] = cvtpk(pr[0], pr[1]);
        pbp[st][1] = cvtpk(pr[2], pr[3]);
      }
#pragma unroll
      for (int d = 0; d < 4; d++)
#pragma unroll
        for (int r = 0; r < 4; r++) oacc[d][r] *= scale[r];
    }

    // P through per-wave LDS, then PV
#pragma unroll
    for (int st = 0; st < 4; st++) {
#pragma unroll
      for (int rp = 0; rp < 2; rp++) {
        int row0 = lg * 4 + rp * 2;
        int cbyte = (st * 16 + lr) * 2;
        *(unsigned short*)(Pls[w] + row0 * 128 + (cbyte ^ ((row0 & 7) << 4))) =
            (unsigned short)pbp[st][rp];
        int row1 = row0 + 1;
        *(unsigned short*)(Pls[w] + row1 * 128 + (cbyte ^ ((row1 & 7) << 4))) =
            (unsigned short)(pbp[st][rp] >> 16);
      }
    }
    __builtin_amdgcn_s_setprio(1);
#pragma unroll
    for (int ks = 0; ks < 2; ks++) {
      bf16x8 pf = *(const bf16x8*)(Pls[w] + lr * 128 +
                                   (((ks * 4 + lg) ^ (lr & 7)) << 4));
#pragma unroll
      for (int d = 0; d < 4; d++) {
        int row = d * 16 + lr;
        bf16x8 vf = *(const bf16x8*)(VTls[cur] + row * 128 +
                                     (((ks * 4 + lg) ^ (row & 7)) << 4));
        oacc[d] = __builtin_amdgcn_mfma_f32_16x16x32_bf16(pf, vf, oacc[d], 0, 0, 0);
      }
    }
    __builtin_amdgcn_s_setprio(0);

    // T4: counted drain — keep the freshest stage's 2 loads in flight
    if (t + 2 < 16) {
      asm volatile("s_waitcnt vmcnt(2)" ::: "memory");
    } else {
      asm volatile("s_waitcnt vmcnt(0)" ::: "memory");
    }
    __builtin_amdgcn_sched_barrier(0);
    __builtin_amdgcn_s_barrier();
    __builtin_amdgcn_sched_barrier(0);
  }

  // reduce per-lane partial lsum across the 16 lanes of each row group
  float inv[4];
#pragma unroll
  for (int r = 0; r < 4; r++) {
    float s = lsum[r];
#pragma unroll
    for (int o = 1; o < 16; o <<= 1) s += __shfl_xor(s, o, 64);
    inv[r] = (s > 0.f) ? 1.f / s : 0.f;
  }
#pragma unroll
  for (int d = 0; d < 4; d++)
#pragma unroll
    for (int r = 0; r < 4; r++) {
      int t = t0 + w * 16 + lg * 4 + r;
      ow[((size_t)b * 1024 + t) * 512 + h * 64 + d * 16 + lr] = cvt1(oacc[d][r] * inv[r]);
    }
}

extern "C" void kernel_launch(void* const* d_in, const int* in_sizes, int n_in,
                              void* d_out, int out_size, void* d_ws, size_t ws_size,
                              hipStream_t stream) {
  const float* query = (const float*)d_in[0];
  const float* key = (const float*)d_in[1];
  const float* value = (const float*)d_in[2];
  const int* amask = (const int*)d_in[3];
  const float* pos = (const float*)d_in[4];
  const float* Wq = (const float*)d_in[5];
  const float* bq = (const float*)d_in[6];
  const float* Wk = (const float*)d_in[7];
  const float* bk = (const float*)d_in[8];
  const float* Wv = (const float*)d_in[9];
  const float* bv = (const float*)d_in[10];
  const float* Wpos = (const float*)d_in[11];
  const float* Wout = (const float*)d_in[12];
  const float* bout = (const float*)d_in[13];
  const float* pbu = (const float*)d_in[14];
  const float* pbv = (const float*)d_in[15];

  float* out = (float*)d_out;               // [8192,512] f32
  float* cache = out + (size_t)8192 * 512;  // [64,1024,128] f32

  char* ws = (char*)d_ws;
  const size_t SZ = 8388608;  // one bf16 [B,H,T,DK] tensor
  dim3 blk(256);

  if (ws_size >= 8 * SZ + 1310720) {
    // ---- big-workspace path: pre-convert activations, all-bf16 GEMM ----
    unsigned short* Xb = (unsigned short*)(ws);              // 4 x 8.39 MB
    unsigned short* ws_q = (unsigned short*)(ws + 4 * SZ);
    unsigned short* ws_kp = (unsigned short*)(ws + 5 * SZ);
    unsigned short* ws_vt = (unsigned short*)(ws + 6 * SZ);
    unsigned short* ws_o = (unsigned short*)(ws + 7 * SZ);
    unsigned short* W4 = ws_o;                               // alias, dead before attn
    float* cbuf = (float*)(ws + 8 * SZ);
    unsigned long long* mbits = (unsigned long long*)(ws + 8 * SZ + 262144);
    unsigned short* Woutb = Xb;                              // X dead after qkvp gemm

    prep_cast<<<dim3(128, 4), blk, 0, stream>>>(Wq, Wk, Wv, Wpos, W4, 262144);
    prep_cast<<<dim3(2048, 4), blk, 0, stream>>>(query, key, value, pos, Xb, 4194304);
    gemm_bt<false, true><<<dim3(2048), blk, 0, stream>>>(
        Xb, Xb + 4194304, Xb + 8388608, Xb + 12582912, W4, bq, bk, bv, 0,
        ws_q, cache, ws_vt, ws_kp, nullptr);
    fuse_kp<<<dim3(4096), blk, 0, stream>>>(cache, ws_kp, pbu, pbv, cbuf);
    pack_mask<<<dim3(32768), blk, 0, stream>>>(amask, mbits);
    attn_kernel<<<dim3(512), dim3(512), 0, stream>>>(ws_q, ws_kp, ws_vt, cbuf, mbits, ws_o);
    prep_cast<<<dim3(128, 1), blk, 0, stream>>>(Wout, Wout, Wout, Wout, Woutb, 262144);
    gemm_bt<false, false><<<dim3(64, 8, 1), blk, 0, stream>>>(
        ws_o, nullptr, nullptr, nullptr, Woutb, bout, nullptr, nullptr, 4,
        nullptr, nullptr, nullptr, nullptr, out);
  } else {
    // ---- fallback: R6 layout (f32 A staged through regs) ----
    unsigned short* ws_q = (unsigned short*)(ws);
    unsigned short* ws_kp = (unsigned short*)(ws + SZ);
    unsigned short* ws_vt = (unsigned short*)(ws + 2 * SZ);
    unsigned short* ws_o = (unsigned short*)(ws + 3 * SZ);
    unsigned short* W4 = ws_o;
    float* cbuf = (float*)(ws + 4 * SZ);
    unsigned long long* mbits = (unsigned long long*)(ws + 4 * SZ + 262144);
    unsigned short* Woutb = ws_q;

    prep_cast<<<dim3(128, 4), blk, 0, stream>>>(Wq, Wk, Wv, Wpos, W4, 262144);
    gemm_bt<true, false><<<dim3(64, 8, 4), blk, 0, stream>>>(
        query, key, value, pos, W4, bq, bk, bv, 0, ws_q, cache, ws_vt, ws_kp, nullptr);
    fuse_kp<<<dim3(4096), blk, 0, stream>>>(cache, ws_kp, pbu, pbv, cbuf);
    pack_mask<<<dim3(32768), blk, 0, stream>>>(amask, mbits);
    attn_kernel<<<dim3(512), dim3(512), 0, stream>>>(ws_q, ws_kp, ws_vt, cbuf, mbits, ws_o);
    prep_cast<<<dim3(128, 1), blk, 0, stream>>>(Wout, Wout, Wout, Wout, Woutb, 262144);
    gemm_bt<false, false><<<dim3(64, 8, 1), blk, 0, stream>>>(
        ws_o, nullptr, nullptr, nullptr, Woutb, bout, nullptr, nullptr, 4,
        nullptr, nullptr, nullptr, nullptr, out);
  }
}

// Round 12
// 125.535 us; speedup vs baseline: 1.1012x; 1.1012x over previous
//
#include <hip/hip_runtime.h>

typedef __attribute__((ext_vector_type(8))) short bf16x8;
typedef __attribute__((ext_vector_type(4))) float f32x4;
typedef __attribute__((ext_vector_type(16))) float f32x16;
typedef __attribute__((ext_vector_type(4))) unsigned int u32x4;
typedef __attribute__((ext_vector_type(4))) unsigned short u16x4;

#define DEVFN static __device__ __forceinline__

DEVFN unsigned cvtpk(float lo, float hi) {
  unsigned r;
  asm("v_cvt_pk_bf16_f32 %0, %1, %2" : "=v"(r) : "v"(lo), "v"(hi));
  return r;
}
DEVFN unsigned short cvt1(float x) {
  unsigned r;
  asm("v_cvt_pk_bf16_f32 %0, %1, %1" : "=v"(r) : "v"(x));
  return (unsigned short)r;
}
DEVFN float fexp2(float x) {
  float r;
  asm("v_exp_f32 %0, %1" : "=v"(r) : "v"(x));
  return r;
}
DEVFN float bf2f(unsigned short s) { return __uint_as_float(((unsigned)s) << 16); }

DEVFN void gld16(const void* g, void* l) {
  __builtin_amdgcn_global_load_lds(
      (const __attribute__((address_space(1))) unsigned int*)g,
      (__attribute__((address_space(3))) unsigned int*)l, 16, 0, 0);
}

__global__ __launch_bounds__(256, 8) void prep_cast(
    const float* __restrict__ s0, const float* __restrict__ s1,
    const float* __restrict__ s2, const float* __restrict__ s3,
    unsigned short* __restrict__ dst, int perMat) {
  const float* s = blockIdx.y == 0 ? s0 : blockIdx.y == 1 ? s1
                   : blockIdx.y == 2 ? s2 : s3;
  size_t base = (size_t)blockIdx.y * perMat;
  size_t idx = ((size_t)blockIdx.x * 256 + threadIdx.x) * 8;
  float4 a = *(const float4*)(s + idx);
  float4 b = *(const float4*)(s + idx + 4);
  uint4 o;
  o.x = cvtpk(a.x, a.y); o.y = cvtpk(a.z, a.w);
  o.z = cvtpk(b.x, b.y); o.w = cvtpk(b.z, b.w);
  *(uint4*)(dst + base + idx) = o;
}

// ---- GEMM: unchanged from R9 ----
template <bool AF32, bool SWZ>
__global__ __launch_bounds__(256, 3) void gemm_bt(
    const void* A0, const void* A1, const void* A2, const void* A3,
    const unsigned short* __restrict__ Wb, const float* b0, const float* b1,
    const float* b2, int mode_base,
    unsigned short* __restrict__ qout, float* __restrict__ cache,
    unsigned short* __restrict__ vtout, unsigned short* __restrict__ pout,
    float* __restrict__ fout) {
  __shared__ alignas(16) char Als[2][128 * 128];
  __shared__ alignas(16) char Bls[2][64 * 128];
  const int tid = threadIdx.x;
  const int lane = tid & 63, w = tid >> 6;
  const int wr = (w >> 1) * 64, wc = (w & 1) * 32;
  const int lg = lane >> 4, lr = lane & 15;
  int m0, n0, mz;
  if constexpr (SWZ) {
    int id = blockIdx.x;
    int xcd = id & 7, j = id >> 3;
    n0 = (j & 7) * 64;
    mz = (j >> 3) & 3;
    m0 = (xcd * 8 + (j >> 5)) * 128;
  } else {
    m0 = blockIdx.x * 128;
    n0 = blockIdx.y * 64;
    mz = blockIdx.z;
  }
  const int mode = mode_base + mz;
  const void* Ap = (mode == 1) ? A1 : (mode == 2) ? A2 : (mode == 3) ? A3 : A0;
  const unsigned short* Wp = Wb + (size_t)mz * 262144;
  const float* bias = (mode == 0 || mode == 4) ? b0
                      : (mode == 1) ? b1 : (mode == 2) ? b2 : nullptr;

  float4 ra[8];
  auto loadA = [&](int k0) {
    const float* Af = (const float*)Ap;
#pragma unroll
    for (int rep = 0; rep < 4; rep++) {
      int cid = rep * 256 + tid;
      int row = cid >> 3, c = cid & 7;
      const float* src = Af + (size_t)(m0 + row) * 512 + k0 + c * 8;
      ra[rep * 2] = *(const float4*)(src);
      ra[rep * 2 + 1] = *(const float4*)(src + 4);
    }
  };
  auto writeA = [&](int buf) {
#pragma unroll
    for (int rep = 0; rep < 4; rep++) {
      int cid = rep * 256 + tid;
      int row = cid >> 3, c = cid & 7;
      uint4 o;
      o.x = cvtpk(ra[rep * 2].x, ra[rep * 2].y);
      o.y = cvtpk(ra[rep * 2].z, ra[rep * 2].w);
      o.z = cvtpk(ra[rep * 2 + 1].x, ra[rep * 2 + 1].y);
      o.w = cvtpk(ra[rep * 2 + 1].z, ra[rep * 2 + 1].w);
      *(uint4*)(Als[buf] + row * 128 + ((c ^ (row & 7)) << 4)) = o;
    }
  };
  auto stageA_lds = [&](int buf, int k0) {
    const unsigned short* Ab = (const unsigned short*)Ap;
#pragma unroll
    for (int rep = 0; rep < 4; rep++) {
      int cid = rep * 256 + tid;
      int row = cid >> 3, c = cid & 7;
      gld16(Ab + (size_t)(m0 + row) * 512 + k0 + ((c ^ (row & 7)) << 3),
            Als[buf] + ((rep * 256 + (w << 6)) << 4));
    }
  };
  auto stageB = [&](int buf, int k0) {
#pragma unroll
    for (int rep = 0; rep < 2; rep++) {
      int cid = rep * 256 + tid;
      int row = cid >> 3, c = cid & 7;
      gld16(Wp + (size_t)(n0 + row) * 512 + k0 + ((c ^ (row & 7)) << 3),
            Bls[buf] + ((rep * 256 + (w << 6)) << 4));
    }
  };

  f32x4 acc[4][2];
#pragma unroll
  for (int i = 0; i < 4; i++)
#pragma unroll
    for (int j = 0; j < 2; j++) acc[i][j] = (f32x4)(0.f);

  if constexpr (AF32) { loadA(0); writeA(0); } else { stageA_lds(0, 0); }
  stageB(0, 0);
  __syncthreads();
  int cur = 0;
  for (int k0 = 0; k0 < 512; k0 += 64) {
    bool more = (k0 + 64 < 512);
    if (more) {
      if constexpr (AF32) loadA(k0 + 64); else stageA_lds(cur ^ 1, k0 + 64);
      stageB(cur ^ 1, k0 + 64);
    }
#pragma unroll
    for (int ks = 0; ks < 2; ks++) {
      bf16x8 af[4], bfr[2];
#pragma unroll
      for (int i = 0; i < 4; i++) {
        int row = wr + i * 16 + lr;
        af[i] = *(const bf16x8*)(Als[cur] + row * 128 + (((ks * 4 + lg) ^ (row & 7)) << 4));
      }
#pragma unroll
      for (int j = 0; j < 2; j++) {
        int row = wc + j * 16 + lr;
        bfr[j] = *(const bf16x8*)(Bls[cur] + row * 128 + (((ks * 4 + lg) ^ (row & 7)) << 4));
      }
#pragma unroll
      for (int i = 0; i < 4; i++)
#pragma unroll
        for (int j = 0; j < 2; j++)
          acc[i][j] = __builtin_amdgcn_mfma_f32_16x16x32_bf16(af[i], bfr[j],
                                                              acc[i][j], 0, 0, 0);
    }
    if (more) { if constexpr (AF32) writeA(cur ^ 1); }
    __syncthreads();
    cur ^= 1;
  }

#pragma unroll
  for (int i = 0; i < 4; i++) {
#pragma unroll
    for (int j = 0; j < 2; j++) {
      int colg = n0 + wc + j * 16 + lr;
      float bc = bias ? bias[colg] : 0.f;
      if (mode == 4) {
#pragma unroll
        for (int r = 0; r < 4; r++) {
          int rowg = m0 + wr + i * 16 + lg * 4 + r;
          fout[(size_t)rowg * 512 + colg] = acc[i][j][r] + bc;
        }
      } else {
        int rbase = m0 + wr + i * 16 + lg * 4;
        int b = rbase >> 10, t = rbase & 1023, h = colg >> 6, dk = colg & 63;
        size_t bht = (size_t)(b * 8 + h) * 1024 + t;
        if (mode == 0) {
#pragma unroll
          for (int r = 0; r < 4; r++) qout[(bht + r) * 64 + dk] = cvt1(acc[i][j][r] + bc);
        } else if (mode == 1) {
#pragma unroll
          for (int r = 0; r < 4; r++) cache[(bht + r) * 128 + dk] = acc[i][j][r] + bc;
        } else if (mode == 3) {
#pragma unroll
          for (int r = 0; r < 4; r++) pout[(bht + r) * 64 + dk] = cvt1(acc[i][j][r]);
        } else {
          float vv[4];
#pragma unroll
          for (int r = 0; r < 4; r++) {
            vv[r] = acc[i][j][r] + bc;
            cache[(bht + r) * 128 + 64 + dk] = vv[r];
          }
          uint2 pv;
          pv.x = cvtpk(vv[0], vv[1]);
          pv.y = cvtpk(vv[2], vv[3]);
          *(uint2*)(vtout + ((size_t)(b * 8 + h) * 64 + dk) * 1024 + t) = pv;
        }
      }
    }
  }
}

__global__ __launch_bounds__(256, 4) void fuse_kp(
    const float* __restrict__ kcache, unsigned short* __restrict__ kp,
    const float* __restrict__ ub, const float* __restrict__ vb,
    float* __restrict__ cb) {
  int tid = threadIdx.x;
  int row = blockIdx.x * 16 + (tid >> 4);
  int g = tid & 15;
  int h = (row >> 10) & 7;
  float4 k4 = *(const float4*)(kcache + (size_t)row * 128 + g * 4);
  u16x4 p4 = *(const u16x4*)(kp + (size_t)row * 64 + g * 4);
  float4 uu = *(const float4*)(ub + h * 64 + g * 4);
  float4 vv = *(const float4*)(vb + h * 64 + g * 4);
  float kf[4] = {k4.x, k4.y, k4.z, k4.w};
  float uf[4] = {uu.x, uu.y, uu.z, uu.w};
  float vf[4] = {vv.x, vv.y, vv.z, vv.w};
  float part = 0.f;
  float s[4];
#pragma unroll
  for (int j = 0; j < 4; j++) {
    float pf = bf2f((unsigned short)p4[j]);
    s[j] = kf[j] + pf;
    part += uf[j] * kf[j] + vf[j] * pf;
  }
  uint2 o;
  o.x = cvtpk(s[0], s[1]);
  o.y = cvtpk(s[2], s[3]);
  *(uint2*)(kp + (size_t)row * 64 + g * 4) = o;
#pragma unroll
  for (int sft = 1; sft < 16; sft <<= 1) part += __shfl_xor(part, sft, 64);
  if (g == 0) cb[row] = part;
}

__global__ __launch_bounds__(256, 8) void pack_mask(
    const int* __restrict__ m, unsigned long long* __restrict__ mb) {
  int word = blockIdx.x * 4 + (threadIdx.x >> 6);
  int lane = threadIdx.x & 63;
  int v = m[(size_t)(word >> 4) * 1024 + (word & 15) * 64 + lane];
  unsigned long long bal = __ballot(v != 0);
  if (lane == 0) mb[word] = bal;
}

// flash attn, m214-style: 32x32x16 MFMA, swapped QK (S^T in regs), in-register
// softmax, P->A-frag via cvt_pk + __shfl_xor(32) cross-half exchange (no P LDS
// roundtrip). 4 waves x 32 q-rows = 128 q/block. KVBLK=128 dbuf. Grid 512
// XCD-swizzled.
__global__ __launch_bounds__(256, 2) void attn_kernel(
    const unsigned short* __restrict__ qw, const unsigned short* __restrict__ kpw,
    const unsigned short* __restrict__ vtw, const float* __restrict__ cb,
    const unsigned long long* __restrict__ mbits, unsigned short* __restrict__ ow) {
  __shared__ alignas(16) char KPls[2][128 * 128];  // 32 KB
  __shared__ alignas(16) char VTls[2][64 * 256];   // 32 KB
  __shared__ alignas(16) float cvLS[1024];         // 4 KB
  __shared__ alignas(16) float lsLS[4][32];        // 0.5 KB

  const int tid = threadIdx.x;
  const int lane = tid & 63, w = tid >> 6;
  const int hi = lane >> 5, q5 = lane & 31;
  const int l = blockIdx.x;
  const int bh = (l & 7) * 8 + ((l >> 3) >> 3);
  const int t0 = ((l >> 3) & 7) * 128;
  const int b = bh >> 3;
  const int h = bh & 7;
  const float NEG = -3.0e38f;
  const float SC = 0.125f * 1.44269504088896f;
  const float MREF = 24.0f;

  // cvLS[kv] = c[kv]*SC - MREF  (shifted-domain bias)
#pragma unroll
  for (int i = 0; i < 4; i++)
    cvLS[i * 256 + tid] = cb[(size_t)bh * 1024 + i * 256 + tid] * SC - MREF;

  const int qg = t0 + w * 32 + q5;
  const size_t qrow = (size_t)bh * 1024 + qg;
  bf16x8 qf[4];
#pragma unroll
  for (int ks = 0; ks < 4; ks++)
    qf[ks] = *(const bf16x8*)(qw + qrow * 64 + ks * 16 + hi * 8);

  bool wave_full;
  {
    unsigned long long accm = ~0ull;
#pragma unroll
    for (int j = 0; j < 8; j++)
      accm &= mbits[((size_t)b * 1024 + qg) * 16 + hi * 8 + j];
    wave_full = __all(accm == ~0ull);
  }

  f32x16 oacc[2];
#pragma unroll
  for (int dt = 0; dt < 2; dt++) oacc[dt] = (f32x16)(0.f);
  float mrow = 0.f, lsum = 0.f;  // shifted domain; per-lane q = q5

  auto stage = [&](int buf, int s0) {
    const size_t kr0 = (size_t)bh * 1024 + s0;
#pragma unroll
    for (int p = 0; p < 4; p++) {
      int row = p * 32 + (tid >> 3), c = tid & 7;
      gld16(kpw + (kr0 + row) * 64 + ((c ^ (row & 7)) << 3),
            KPls[buf] + p * 4096 + w * 1024);
    }
#pragma unroll
    for (int p = 0; p < 4; p++) {
      int row = p * 16 + (tid >> 4), c = tid & 15;
      gld16(vtw + ((size_t)bh * 64 + row) * 1024 + s0 + ((c ^ (row & 15)) << 3),
            VTls[buf] + p * 4096 + w * 1024);
    }
  };

  stage(0, 0);
  __syncthreads();
  int cur = 0;
  for (int it = 0; it < 8; ++it) {
    const int s0 = it * 128;
    if (it < 7) stage(cur ^ 1, s0 + 128);

#pragma unroll
    for (int t = 0; t < 4; t++) {
      // QK^T (swapped): sacc[reg] = S'[kv = t*32 + (reg&3)+8*(reg>>2)+4*hi][q = q5]
      f32x16 sacc = (f32x16)(0.f);
      const int arow = t * 32 + q5;
      __builtin_amdgcn_s_setprio(1);
#pragma unroll
      for (int ks = 0; ks < 4; ks++) {
        bf16x8 kf = *(const bf16x8*)(KPls[cur] + arow * 128 +
                                     (((ks * 2 + hi) ^ (arow & 7)) << 4));
        sacc = __builtin_amdgcn_mfma_f32_32x32x16_bf16(kf, qf[ks], sacc, 0, 0, 0);
      }
      __builtin_amdgcn_s_setprio(0);

      float p[16];
      if (wave_full) {
        float ls = 0.f;
#pragma unroll
        for (int rb = 0; rb < 4; rb++) {
          f32x4 cv4 = *(const f32x4*)(cvLS + s0 + t * 32 + rb * 8 + hi * 4);
#pragma unroll
          for (int j = 0; j < 4; j++) {
            int reg = rb * 4 + j;
            p[reg] = fexp2(fmaf(sacc[reg], SC, cv4[j]));
            ls += p[reg];
          }
        }
        lsum += ls;
      } else {
        unsigned long long mw =
            mbits[((size_t)b * 1024 + qg) * 16 + ((s0 + t * 32) >> 6)];
        const int bbase = (t & 1) * 32;
        float s_[16];
        float mx = NEG;
#pragma unroll
        for (int rb = 0; rb < 4; rb++) {
          f32x4 cv4 = *(const f32x4*)(cvLS + s0 + t * 32 + rb * 8 + hi * 4);
#pragma unroll
          for (int j = 0; j < 4; j++) {
            int reg = rb * 4 + j;
            s_[reg] = fmaf(sacc[reg], SC, cv4[j]);
            if ((mw >> (bbase + rb * 8 + hi * 4 + j)) & 1ull)
              mx = fmaxf(mx, s_[reg]);
          }
        }
        mx = fmaxf(mx, __shfl_xor(mx, 32, 64));
        float mn = fmaxf(mrow, mx);
        float sc = (mn == mrow) ? 1.f : fexp2(mrow - mn);
        mrow = mn;
        lsum *= sc;
#pragma unroll
        for (int rb = 0; rb < 4; rb++)
#pragma unroll
          for (int j = 0; j < 4; j++) {
            int reg = rb * 4 + j;
            bool on = (mw >> (bbase + rb * 8 + hi * 4 + j)) & 1ull;
            p[reg] = on ? fexp2(s_[reg] - mn) : 0.f;
            lsum += p[reg];
          }
        // redistribute per-q scale to per-reg (q = crow) via wave LDS
        if (lane < 32) lsLS[w][q5] = sc;
        asm volatile("s_waitcnt lgkmcnt(0)" ::: "memory");
        __builtin_amdgcn_sched_barrier(0);
#pragma unroll
        for (int rb = 0; rb < 4; rb++) {
          f32x4 s4 = *(const f32x4*)(&lsLS[w][rb * 8 + hi * 4]);
#pragma unroll
          for (int j = 0; j < 4; j++) {
#pragma unroll
            for (int dt = 0; dt < 2; dt++) oacc[dt][rb * 4 + j] *= s4[j];
          }
        }
      }

      // P -> PV A-frag entirely in registers:
      //   lane(hi=0) needs kv 0..7  = (a0,a1, a0@partner, a1@partner)
      //   lane(hi=1) needs kv 8..15 = (b0@partner, b1@partner, b0,b1)
#pragma unroll
      for (int ks16 = 0; ks16 < 2; ks16++) {
        unsigned a0 = cvtpk(p[ks16 * 8 + 0], p[ks16 * 8 + 1]);
        unsigned a1 = cvtpk(p[ks16 * 8 + 2], p[ks16 * 8 + 3]);
        unsigned b0 = cvtpk(p[ks16 * 8 + 4], p[ks16 * 8 + 5]);
        unsigned b1 = cvtpk(p[ks16 * 8 + 6], p[ks16 * 8 + 7]);
        unsigned xa0 = __shfl_xor(a0, 32, 64);
        unsigned xa1 = __shfl_xor(a1, 32, 64);
        unsigned xb0 = __shfl_xor(b0, 32, 64);
        unsigned xb1 = __shfl_xor(b1, 32, 64);
        u32x4 pk4;
        pk4.x = hi ? xb0 : a0;
        pk4.y = hi ? xb1 : a1;
        pk4.z = hi ? b0 : xa0;
        pk4.w = hi ? b1 : xa1;
        bf16x8 af = __builtin_bit_cast(bf16x8, pk4);
        __builtin_amdgcn_s_setprio(1);
#pragma unroll
        for (int dt = 0; dt < 2; dt++) {
          int vrow = dt * 32 + q5;
          int vc = t * 4 + ks16 * 2 + hi;
          bf16x8 vf = *(const bf16x8*)(VTls[cur] + vrow * 256 +
                                       ((vc ^ (vrow & 15)) << 4));
          oacc[dt] = __builtin_amdgcn_mfma_f32_32x32x16_bf16(af, vf, oacc[dt], 0, 0, 0);
        }
        __builtin_amdgcn_s_setprio(0);
      }
    }
    __syncthreads();
    cur ^= 1;
  }

  // normalize: total lsum per q (this lane + partner), redistribute inverse
  float tot = lsum + __shfl_xor(lsum, 32, 64);
  if (lane < 32) lsLS[w][q5] = (tot > 0.f) ? 1.f / tot : 0.f;
  asm volatile("s_waitcnt lgkmcnt(0)" ::: "memory");
  __builtin_amdgcn_sched_barrier(0);
#pragma unroll
  for (int rb = 0; rb < 4; rb++) {
    f32x4 inv4 = *(const f32x4*)(&lsLS[w][rb * 8 + hi * 4]);
#pragma unroll
    for (int j = 0; j < 4; j++) {
      int reg = rb * 4 + j;
      int qo = t0 + w * 32 + rb * 8 + hi * 4 + j;
#pragma unroll
      for (int dt = 0; dt < 2; dt++) {
        ow[((size_t)b * 1024 + qo) * 512 + h * 64 + dt * 32 + q5] =
            cvt1(oacc[dt][reg] * inv4[j]);
      }
    }
  }
}

extern "C" void kernel_launch(void* const* d_in, const int* in_sizes, int n_in,
                              void* d_out, int out_size, void* d_ws, size_t ws_size,
                              hipStream_t stream) {
  const float* query = (const float*)d_in[0];
  const float* key = (const float*)d_in[1];
  const float* value = (const float*)d_in[2];
  const int* amask = (const int*)d_in[3];
  const float* pos = (const float*)d_in[4];
  const float* Wq = (const float*)d_in[5];
  const float* bq = (const float*)d_in[6];
  const float* Wk = (const float*)d_in[7];
  const float* bk = (const float*)d_in[8];
  const float* Wv = (const float*)d_in[9];
  const float* bv = (const float*)d_in[10];
  const float* Wpos = (const float*)d_in[11];
  const float* Wout = (const float*)d_in[12];
  const float* bout = (const float*)d_in[13];
  const float* pbu = (const float*)d_in[14];
  const float* pbv = (const float*)d_in[15];

  float* out = (float*)d_out;
  float* cache = out + (size_t)8192 * 512;

  char* ws = (char*)d_ws;
  const size_t SZ = 8388608;
  dim3 blk(256);

  if (ws_size >= 8 * SZ + 1310720) {
    unsigned short* Xb = (unsigned short*)(ws);
    unsigned short* ws_q = (unsigned short*)(ws + 4 * SZ);
    unsigned short* ws_kp = (unsigned short*)(ws + 5 * SZ);
    unsigned short* ws_vt = (unsigned short*)(ws + 6 * SZ);
    unsigned short* ws_o = (unsigned short*)(ws + 7 * SZ);
    unsigned short* W4 = ws_o;
    float* cbuf = (float*)(ws + 8 * SZ);
    unsigned long long* mbits = (unsigned long long*)(ws + 8 * SZ + 262144);
    unsigned short* Woutb = Xb;

    prep_cast<<<dim3(128, 4), blk, 0, stream>>>(Wq, Wk, Wv, Wpos, W4, 262144);
    prep_cast<<<dim3(2048, 4), blk, 0, stream>>>(query, key, value, pos, Xb, 4194304);
    gemm_bt<false, true><<<dim3(2048), blk, 0, stream>>>(
        Xb, Xb + 4194304, Xb + 8388608, Xb + 12582912, W4, bq, bk, bv, 0,
        ws_q, cache, ws_vt, ws_kp, nullptr);
    fuse_kp<<<dim3(4096), blk, 0, stream>>>(cache, ws_kp, pbu, pbv, cbuf);
    pack_mask<<<dim3(32768), blk, 0, stream>>>(amask, mbits);
    attn_kernel<<<dim3(512), blk, 0, stream>>>(ws_q, ws_kp, ws_vt, cbuf, mbits, ws_o);
    prep_cast<<<dim3(128, 1), blk, 0, stream>>>(Wout, Wout, Wout, Wout, Woutb, 262144);
    gemm_bt<false, false><<<dim3(64, 8, 1), blk, 0, stream>>>(
        ws_o, nullptr, nullptr, nullptr, Woutb, bout, nullptr, nullptr, 4,
        nullptr, nullptr, nullptr, nullptr, out);
  } else {
    unsigned short* ws_q = (unsigned short*)(ws);
    unsigned short* ws_kp = (unsigned short*)(ws + SZ);
    unsigned short* ws_vt = (unsigned short*)(ws + 2 * SZ);
    unsigned short* ws_o = (unsigned short*)(ws + 3 * SZ);
    unsigned short* W4 = ws_o;
    float* cbuf = (float*)(ws + 4 * SZ);
    unsigned long long* mbits = (unsigned long long*)(ws + 4 * SZ + 262144);
    unsigned short* Woutb = ws_q;

    prep_cast<<<dim3(128, 4), blk, 0, stream>>>(Wq, Wk, Wv, Wpos, W4, 262144);
    gemm_bt<true, false><<<dim3(64, 8, 4), blk, 0, stream>>>(
        query, key, value, pos, W4, bq, bk, bv, 0, ws_q, cache, ws_vt, ws_kp, nullptr);
    fuse_kp<<<dim3(4096), blk, 0, stream>>>(cache, ws_kp, pbu, pbv, cbuf);
    pack_mask<<<dim3(32768), blk, 0, stream>>>(amask, mbits);
    attn_kernel<<<dim3(512), blk, 0, stream>>>(ws_q, ws_kp, ws_vt, cbuf, mbits, ws_o);
    prep_cast<<<dim3(128, 1), blk, 0, stream>>>(Wout, Wout, Wout, Wout, Woutb, 262144);
    gemm_bt<false, false><<<dim3(64, 8, 1), blk, 0, stream>>>(
        ws_o, nullptr, nullptr, nullptr, Woutb, bout, nullptr, nullptr, 4,
        nullptr, nullptr, nullptr, nullptr, out);
  }
}